// Round 3
// baseline (169.916 us; speedup 1.0000x reference)
//
#include <hip/hip_runtime.h>

#define B_ 8
#define T_ 2048
#define H_ 256
#define PSTR 40                  // P LDS row stride (elems)
#define SCALE2 0.0901684403f     // (1/16) * log2(e)
#define SLOPE2 0.00563552752f    // 2^-8 * log2(e)
#define ELEMS ((size_t)B_ * T_ * H_)

typedef __attribute__((ext_vector_type(8))) short bf16x8;
typedef __attribute__((ext_vector_type(4))) float f32x4;

#define MFMA16(a, b, c) __builtin_amdgcn_mfma_f32_16x16x32_bf16((a), (b), (c), 0, 0, 0)

__device__ __forceinline__ ushort f2bf(float f) {
  unsigned u = __float_as_uint(f);
  u += 0x7FFFu + ((u >> 16) & 1u);   // RNE; finite inputs
  return (ushort)(u >> 16);
}

// async 16B/lane global->LDS DMA (contiguous: LDS = uniform base + lane*16)
__device__ __forceinline__ void gl_lds16(const ushort* g, ushort* l) {
  __builtin_amdgcn_global_load_lds(
      (const __attribute__((address_space(1))) unsigned int*)g,
      (__attribute__((address_space(3))) unsigned int*)l, 16, 0, 0);
}

// ---- prologue: blocks [0,1024) RoPE(k)->bf16 blocked ktile; [1024,2048) v transpose ----
// ktile layout: [b][it=t/32][d8=d/8][kv=t%32][8]   (16KB contiguous per (b,it) tile)
// vtile layout: [b][it][q4=(t%32)/8][h][8]
__global__ void prep_kernel(const float* __restrict__ k, const float* __restrict__ v,
                            ushort* __restrict__ kt, ushort* __restrict__ vt) {
  __shared__ ushort tile[64][72];
  const int bid = blockIdx.x;
  const int tid = threadIdx.x;
  if (bid < 1024) {
    // K RoPE: thread = (bt, d8); reads 2x32B coalesced, writes 2x16B vector stores
    int idx = bid * 256 + tid;          // over B*T*16
    int d8 = idx & 15;
    int bt = idx >> 4;
    int t = bt & (T_ - 1);
    int b = bt >> 11;
    size_t base = (size_t)bt * H_ + d8 * 8;
    float4 a0 = *(const float4*)(k + base);
    float4 a1 = *(const float4*)(k + base + 4);
    float4 c0 = *(const float4*)(k + base + 128);
    float4 c1 = *(const float4*)(k + base + 132);
    float av[8] = {a0.x, a0.y, a0.z, a0.w, a1.x, a1.y, a1.z, a1.w};
    float cv[8] = {c0.x, c0.y, c0.z, c0.w, c1.x, c1.y, c1.z, c1.w};
    bf16x8 lo, hi;
#pragma unroll
    for (int e = 0; e < 8; ++e) {
      int j = d8 * 8 + e;
      float rv = (float)t * exp2f((float)j * -0.103810252959f) * 0.15915494309f;
      float fr = rv - floorf(rv);
      float sn = __builtin_amdgcn_sinf(fr), cs = __builtin_amdgcn_cosf(fr);
      lo[e] = (short)f2bf(av[e] * cs - cv[e] * sn);
      hi[e] = (short)f2bf(cv[e] * cs + av[e] * sn);
    }
    size_t kdst = (((size_t)(b * 64 + (t >> 5)) * 32 + d8) * 32 + (t & 31)) * 8;
    *(bf16x8*)(kt + kdst) = lo;
    *(bf16x8*)(kt + kdst + 4096) = hi;   // d8 + 16
  } else {
    // V transpose into blocked vtile, 64x64 tiles, XOR-8 swizzle in LDS
    int bid2 = bid - 1024;
    int b = bid2 >> 7, rem = bid2 & 127;
    int h0 = (rem >> 5) * 64, t0 = (rem & 31) * 64;
    int c4 = tid & 15, r0 = tid >> 4;
#pragma unroll
    for (int p = 0; p < 4; ++p) {
      int row = r0 + p * 16;
      const float4 f = *(const float4*)(v + ((size_t)(b * T_ + t0 + row)) * H_ + h0 + c4 * 4);
      ushort4 u;
      u.x = f2bf(f.x); u.y = f2bf(f.y); u.z = f2bf(f.z); u.w = f2bf(f.w);
      *(ushort4*)&tile[row][(c4 * 4) ^ (8 * ((row >> 3) & 7))] = u;
    }
    __syncthreads();
#pragma unroll
    for (int p = 0; p < 2; ++p) {
      int c = tid + p * 256;
      int h = c >> 3, tc = (c & 7) * 8;
      int xo = 8 * (c & 7);
      ushort4 u0, u1;
      u0.x = tile[tc + 0][h ^ xo]; u0.y = tile[tc + 1][h ^ xo];
      u0.z = tile[tc + 2][h ^ xo]; u0.w = tile[tc + 3][h ^ xo];
      u1.x = tile[tc + 4][h ^ xo]; u1.y = tile[tc + 5][h ^ xo];
      u1.z = tile[tc + 6][h ^ xo]; u1.w = tile[tc + 7][h ^ xo];
      int tg = t0 + tc;
      size_t dst = (((size_t)(b * 64 + (tg >> 5)) * 4 + ((tg >> 3) & 3)) * 256 + (h0 + h)) * 8;
      *(ushort4*)(vt + dst) = u0;
      *(ushort4*)(vt + dst + 4) = u1;
    }
  }
}

// ---- Flash attention: 256-thr blocks, 4 waves x 32 q-rows (mt=2 reuse:
// 34 ds_read per 66 MFMA), q-tile 128, kv-split 2. Grid (8,16,2)=256 blocks
// = 1 block/CU. T15 pipeline: softmax+PV of tile(it-1) overlapped under
// QK(it) in the same BB; V triple-buffered (slot t%3), K double-buffered.
// Counted vmcnt(8) acquire, lgkm-only release, prefetch distance 2.
__global__ __launch_bounds__(256, 1)
void attn_kernel(const float* __restrict__ q, const ushort* __restrict__ kt,
                 const ushort* __restrict__ vt, float* __restrict__ out,
                 float* __restrict__ o1, float* __restrict__ lpart) {
  __shared__ ushort Ksh[2][8192];       // [buf][d8][kv32][8]  32 KB
  __shared__ ushort Vsh[3][8192];       // [slot][q4][h256][8] 48 KB
  __shared__ ushort Psh[4][32 * PSTR];  // per-wave P          10 KB

  const int tid = threadIdx.x;
  const int w = tid >> 6, lane = tid & 63, quad = lane >> 4, l16 = lane & 15;
  const int b = blockIdx.x;             // linear%8==b -> XCD affinity
  const int q0 = blockIdx.y * 128;
  const int sp = blockIdx.z;
  const int kvb = sp * (T_ / 2);

  // ---- in-register RoPE of this wave's 32 Q rows into A-frags ----
  bf16x8 aq[2][8];
  {
    const float* qb = q + ((size_t)(b * T_) + q0 + w * 32) * H_;
#pragma unroll
    for (int mt = 0; mt < 2; ++mt) {
      int t = q0 + w * 32 + mt * 16 + l16;
      float qv[8][8];
#pragma unroll
      for (int ks = 0; ks < 8; ++ks) {
        float4 x0 = *(const float4*)(qb + (size_t)(mt * 16 + l16) * H_ + ks * 32 + quad * 8);
        float4 x1 = *(const float4*)(qb + (size_t)(mt * 16 + l16) * H_ + ks * 32 + quad * 8 + 4);
        qv[ks][0] = x0.x; qv[ks][1] = x0.y; qv[ks][2] = x0.z; qv[ks][3] = x0.w;
        qv[ks][4] = x1.x; qv[ks][5] = x1.y; qv[ks][6] = x1.z; qv[ks][7] = x1.w;
      }
#pragma unroll
      for (int ks = 0; ks < 4; ++ks)
#pragma unroll
        for (int e = 0; e < 8; ++e) {
          int d = ks * 32 + quad * 8 + e;
          float rv = (float)t * exp2f((float)d * -0.103810252959f) * 0.15915494309f;
          float fr = rv - floorf(rv);
          float sn = __builtin_amdgcn_sinf(fr), cs = __builtin_amdgcn_cosf(fr);
          aq[mt][ks][e]     = (short)f2bf(qv[ks][e] * cs - qv[ks + 4][e] * sn);
          aq[mt][ks + 4][e] = (short)f2bf(qv[ks + 4][e] * cs + qv[ks][e] * sn);
        }
    }
  }

  const f32x4 fzero = {0.f, 0.f, 0.f, 0.f};
  f32x4 O[2][16], lac[2];
#pragma unroll
  for (int mt = 0; mt < 2; ++mt) {
    lac[mt] = fzero;
#pragma unroll
    for (int ht = 0; ht < 16; ++ht) O[mt][ht] = fzero;
  }
  bf16x8 vones;
#pragma unroll
  for (int i = 0; i < 8; ++i) vones[i] = (short)0x3F80;

  const ushort* ktb = kt + (size_t)(b * 64 + sp * 32) * 8192;
  const ushort* vtb = vt + (size_t)(b * 64 + sp * 32) * 8192;
  const int stoff = tid * 8;            // elems: lane*16B over 256 threads (4KB/round)

  // preload tiles 0,1 -> Ksh[0,1], Vsh[0,1]  (8 DMA per thread per tile)
#pragma unroll
  for (int tt = 0; tt < 2; ++tt) {
    const ushort* kg = ktb + (size_t)tt * 8192;
    const ushort* vg = vtb + (size_t)tt * 8192;
#pragma unroll
    for (int i = 0; i < 4; ++i) {
      gl_lds16(kg + stoff + i * 2048, &Ksh[tt][stoff + i * 2048]);
      gl_lds16(vg + stoff + i * 2048, &Vsh[tt][stoff + i * 2048]);
    }
  }

  const float arb = SLOPE2 * (float)(q0 + w * 32 + quad * 4);
  f32x4 s_prev[2][2] = {{fzero, fzero}, {fzero, fzero}};

  // ---- iter 0 (peeled): QK only ----
  {
    __builtin_amdgcn_sched_barrier(0);
    __builtin_amdgcn_s_waitcnt(0x0F78);   // vmcnt(8): tile0 landed, tile1 in flight
    __builtin_amdgcn_s_barrier();
    __builtin_amdgcn_sched_barrier(0);
#pragma unroll
    for (int ks = 0; ks < 8; ++ks)
#pragma unroll
      for (int nt = 0; nt < 2; ++nt) {
        bf16x8 kf = *(const bf16x8*)&Ksh[0][((ks * 4 + quad) * 32 + nt * 16 + l16) * 8];
        s_prev[0][nt] = MFMA16(aq[0][ks], kf, s_prev[0][nt]);
        s_prev[1][nt] = MFMA16(aq[1][ks], kf, s_prev[1][nt]);
      }
    __builtin_amdgcn_sched_barrier(0);
    __builtin_amdgcn_s_waitcnt(0xC07F);   // lgkmcnt(0)
    __builtin_amdgcn_s_barrier();
    __builtin_amdgcn_sched_barrier(0);
    // prefetch tile 2 -> Ksh[0], Vsh[2]
    const ushort* kg = ktb + (size_t)2 * 8192;
    const ushort* vg = vtb + (size_t)2 * 8192;
#pragma unroll
    for (int i = 0; i < 4; ++i) {
      gl_lds16(kg + stoff + i * 2048, &Ksh[0][stoff + i * 2048]);
      gl_lds16(vg + stoff + i * 2048, &Vsh[2][stoff + i * 2048]);
    }
  }

  // ---- main loop: QK(it) || softmax+PV(it-1) ----
  for (int it = 1; it < 32; ++it) {
    const int p = it & 1;
    const int vp = (it - 1) % 3;        // V slot holding tile(it-1)
    __builtin_amdgcn_sched_barrier(0);
    if (it == 31) __builtin_amdgcn_s_waitcnt(0x0070);   // vmcnt(0) lgkm(0)
    else          __builtin_amdgcn_s_waitcnt(0x0F78);   // vmcnt(8)
    __builtin_amdgcn_s_barrier();
    __builtin_amdgcn_sched_barrier(0);

    // QK(it) on Ksh[p] — independent of the softmax/PV below; same BB so the
    // scheduler interleaves softmax VALU/trans under the MFMA shadow.
    f32x4 s_cur[2][2] = {{fzero, fzero}, {fzero, fzero}};
#pragma unroll
    for (int ks = 0; ks < 8; ++ks)
#pragma unroll
      for (int nt = 0; nt < 2; ++nt) {
        bf16x8 kf = *(const bf16x8*)&Ksh[p][((ks * 4 + quad) * 32 + nt * 16 + l16) * 8];
        s_cur[0][nt] = MFMA16(aq[0][ks], kf, s_cur[0][nt]);
        s_cur[1][nt] = MFMA16(aq[1][ks], kf, s_cur[1][nt]);
      }

    // softmax(it-1): p = exp2(s*SCALE2 + SLOPE2*(col-row)) -> wave-private Psh
#pragma unroll
    for (int nt = 0; nt < 2; ++nt) {
      float ac = SLOPE2 * (float)(kvb + (it - 1) * 32 + nt * 16 + l16);
#pragma unroll
      for (int mt = 0; mt < 2; ++mt)
#pragma unroll
        for (int r = 0; r < 4; ++r) {
          float a0 = ac - arb - SLOPE2 * (float)(mt * 16 + r);
          float pv = __builtin_amdgcn_exp2f(fmaf(s_prev[mt][nt][r], SCALE2, a0));
          Psh[w][(mt * 16 + quad * 4 + r) * PSTR + nt * 16 + l16] = f2bf(pv);
        }
    }

    // PV(it-1) + rowsum on Vsh[vp] (each vf feeds 2 MFMAs via mt reuse)
    bf16x8 pf0 = *(const bf16x8*)&Psh[w][l16 * PSTR + quad * 8];
    bf16x8 pf1 = *(const bf16x8*)&Psh[w][(16 + l16) * PSTR + quad * 8];
    lac[0] = MFMA16(pf0, vones, lac[0]);
    lac[1] = MFMA16(pf1, vones, lac[1]);
#pragma unroll
    for (int ht = 0; ht < 16; ++ht) {
      bf16x8 vf = *(const bf16x8*)&Vsh[vp][(quad * 256 + ht * 16 + l16) * 8];
      O[0][ht] = MFMA16(pf0, vf, O[0][ht]);
      O[1][ht] = MFMA16(pf1, vf, O[1][ht]);
    }

    // roll score regs
#pragma unroll
    for (int mt = 0; mt < 2; ++mt)
#pragma unroll
      for (int nt = 0; nt < 2; ++nt) s_prev[mt][nt] = s_cur[mt][nt];

    // release: drain this wave's LDS ops, barrier -> K[p], V[(it+2)%3] free
    __builtin_amdgcn_sched_barrier(0);
    __builtin_amdgcn_s_waitcnt(0xC07F);   // lgkmcnt(0)
    __builtin_amdgcn_s_barrier();
    __builtin_amdgcn_sched_barrier(0);

    // prefetch tile(it+2) -> Ksh[p], Vsh[(it+2)%3]  (== (it-1)%3, just drained)
    if (it <= 29) {
      const ushort* kg = ktb + (size_t)(it + 2) * 8192;
      const ushort* vg = vtb + (size_t)(it + 2) * 8192;
      ushort* vd = &Vsh[(it + 2) % 3][0];
#pragma unroll
      for (int i = 0; i < 4; ++i) {
        gl_lds16(kg + stoff + i * 2048, &Ksh[p][stoff + i * 2048]);
        gl_lds16(vg + stoff + i * 2048, vd + stoff + i * 2048);
      }
    }
  }

  // ---- tail: softmax(31) + PV(31) on Vsh[31%3=1] ----
  {
#pragma unroll
    for (int nt = 0; nt < 2; ++nt) {
      float ac = SLOPE2 * (float)(kvb + 31 * 32 + nt * 16 + l16);
#pragma unroll
      for (int mt = 0; mt < 2; ++mt)
#pragma unroll
        for (int r = 0; r < 4; ++r) {
          float a0 = ac - arb - SLOPE2 * (float)(mt * 16 + r);
          float pv = __builtin_amdgcn_exp2f(fmaf(s_prev[mt][nt][r], SCALE2, a0));
          Psh[w][(mt * 16 + quad * 4 + r) * PSTR + nt * 16 + l16] = f2bf(pv);
        }
    }
    bf16x8 pf0 = *(const bf16x8*)&Psh[w][l16 * PSTR + quad * 8];
    bf16x8 pf1 = *(const bf16x8*)&Psh[w][(16 + l16) * PSTR + quad * 8];
    lac[0] = MFMA16(pf0, vones, lac[0]);
    lac[1] = MFMA16(pf1, vones, lac[1]);
#pragma unroll
    for (int ht = 0; ht < 16; ++ht) {
      bf16x8 vf = *(const bf16x8*)&Vsh[1][(quad * 256 + ht * 16 + l16) * 8];
      O[0][ht] = MFMA16(pf0, vf, O[0][ht]);
      O[1][ht] = MFMA16(pf1, vf, O[1][ht]);
    }
  }

  // epilogue: unnormalized O-partial + l-partial
  float* od = (sp == 0) ? out : o1;
  float* ob = od + ((size_t)(b * T_) + q0 + w * 32) * H_;
#pragma unroll
  for (int mt = 0; mt < 2; ++mt)
#pragma unroll
    for (int r = 0; r < 4; ++r) {
      int row = mt * 16 + quad * 4 + r;
#pragma unroll
      for (int ht = 0; ht < 16; ++ht)
        ob[(size_t)row * H_ + ht * 16 + l16] = O[mt][ht][r];
    }
  if (l16 == 0) {
#pragma unroll
    for (int mt = 0; mt < 2; ++mt)
#pragma unroll
      for (int r = 0; r < 4; ++r)
        lpart[(size_t)(sp * B_ + b) * T_ + q0 + w * 32 + mt * 16 + quad * 4 + r] =
            lac[mt][r];
    }
}

// ---- combine: out = (O0 + O1) / (l0 + l1) ----
__global__ void combine_kernel(float* __restrict__ out, const float* __restrict__ o1,
                               const float* __restrict__ lpart) {
  int idx = blockIdx.x * 256 + threadIdx.x;   // over B*T*H/4
  int row = idx >> 6;
  float inv = 1.0f / (lpart[row] + lpart[B_ * T_ + row]);
  float4 a = ((const float4*)out)[idx];
  float4 c = ((const float4*)o1)[idx];
  a.x = (a.x + c.x) * inv; a.y = (a.y + c.y) * inv;
  a.z = (a.z + c.z) * inv; a.w = (a.w + c.w) * inv;
  ((float4*)out)[idx] = a;
}

extern "C" void kernel_launch(void* const* d_in, const int* in_sizes, int n_in,
                              void* d_out, int out_size, void* d_ws, size_t ws_size,
                              hipStream_t stream) {
  const float* q = (const float*)d_in[0];
  const float* k = (const float*)d_in[1];
  const float* v = (const float*)d_in[2];
  float* out = (float*)d_out;

  ushort* kt = (ushort*)d_ws;
  ushort* vt = kt + ELEMS;
  float* o1 = (float*)(vt + ELEMS);
  float* lpart = o1 + ELEMS;            // 2*B*T floats

  prep_kernel<<<dim3(2048), 256, 0, stream>>>(k, v, kt, vt);
  attn_kernel<<<dim3(B_, T_ / 128, 2), 256, 0, stream>>>(q, kt, vt, out, o1, lpart);
  combine_kernel<<<dim3((B_ * T_ * H_ / 4) / 256), 256, 0, stream>>>(out, o1, lpart);
}

// Round 4
// 153.431 us; speedup vs baseline: 1.1074x; 1.1074x over previous
//
#include <hip/hip_runtime.h>

#define B_ 8
#define T_ 2048
#define H_ 256
#define PSTR 40                  // P LDS row stride (elems)
#define SCALE2 0.0901684403f     // (1/16) * log2(e)
#define SLOPE2 0.00563552752f    // 2^-8 * log2(e)
#define ELEMS ((size_t)B_ * T_ * H_)

typedef __attribute__((ext_vector_type(8))) short bf16x8;
typedef __attribute__((ext_vector_type(4))) float f32x4;

#define MFMA16(a, b, c) __builtin_amdgcn_mfma_f32_16x16x32_bf16((a), (b), (c), 0, 0, 0)

__device__ __forceinline__ ushort f2bf(float f) {
  unsigned u = __float_as_uint(f);
  u += 0x7FFFu + ((u >> 16) & 1u);   // RNE; finite inputs
  return (ushort)(u >> 16);
}

// async 16B/lane global->LDS DMA (contiguous: LDS = uniform base + lane*16)
__device__ __forceinline__ void gl_lds16(const ushort* g, ushort* l) {
  __builtin_amdgcn_global_load_lds(
      (const __attribute__((address_space(1))) unsigned int*)g,
      (__attribute__((address_space(3))) unsigned int*)l, 16, 0, 0);
}

// ---- prologue: blocks [0,1024) RoPE(k)->bf16 blocked ktile; [1024,2048) v transpose ----
// ktile layout: [b][it=t/32][d8=d/8][kv=t%32][8]   (16KB contiguous per (b,it) tile)
// vtile layout: [b][it][q4=(t%32)/8][h][8]
__global__ void prep_kernel(const float* __restrict__ k, const float* __restrict__ v,
                            ushort* __restrict__ kt, ushort* __restrict__ vt) {
  __shared__ ushort tile[64][72];
  const int bid = blockIdx.x;
  const int tid = threadIdx.x;
  if (bid < 1024) {
    // K RoPE: thread = (bt, d8); reads 2x32B coalesced, writes 2x16B vector stores
    int idx = bid * 256 + tid;          // over B*T*16
    int d8 = idx & 15;
    int bt = idx >> 4;
    int t = bt & (T_ - 1);
    int b = bt >> 11;
    size_t base = (size_t)bt * H_ + d8 * 8;
    float4 a0 = *(const float4*)(k + base);
    float4 a1 = *(const float4*)(k + base + 4);
    float4 c0 = *(const float4*)(k + base + 128);
    float4 c1 = *(const float4*)(k + base + 132);
    float av[8] = {a0.x, a0.y, a0.z, a0.w, a1.x, a1.y, a1.z, a1.w};
    float cv[8] = {c0.x, c0.y, c0.z, c0.w, c1.x, c1.y, c1.z, c1.w};
    bf16x8 lo, hi;
#pragma unroll
    for (int e = 0; e < 8; ++e) {
      int j = d8 * 8 + e;
      float rv = (float)t * exp2f((float)j * -0.103810252959f) * 0.15915494309f;
      float fr = rv - floorf(rv);
      float sn = __builtin_amdgcn_sinf(fr), cs = __builtin_amdgcn_cosf(fr);
      lo[e] = (short)f2bf(av[e] * cs - cv[e] * sn);
      hi[e] = (short)f2bf(cv[e] * cs + av[e] * sn);
    }
    size_t kdst = (((size_t)(b * 64 + (t >> 5)) * 32 + d8) * 32 + (t & 31)) * 8;
    *(bf16x8*)(kt + kdst) = lo;
    *(bf16x8*)(kt + kdst + 4096) = hi;   // d8 + 16
  } else {
    // V transpose into blocked vtile, 64x64 tiles, XOR-8 swizzle in LDS
    int bid2 = bid - 1024;
    int b = bid2 >> 7, rem = bid2 & 127;
    int h0 = (rem >> 5) * 64, t0 = (rem & 31) * 64;
    int c4 = tid & 15, r0 = tid >> 4;
#pragma unroll
    for (int p = 0; p < 4; ++p) {
      int row = r0 + p * 16;
      const float4 f = *(const float4*)(v + ((size_t)(b * T_ + t0 + row)) * H_ + h0 + c4 * 4);
      ushort4 u;
      u.x = f2bf(f.x); u.y = f2bf(f.y); u.z = f2bf(f.z); u.w = f2bf(f.w);
      *(ushort4*)&tile[row][(c4 * 4) ^ (8 * ((row >> 3) & 7))] = u;
    }
    __syncthreads();
#pragma unroll
    for (int p = 0; p < 2; ++p) {
      int c = tid + p * 256;
      int h = c >> 3, tc = (c & 7) * 8;
      int xo = 8 * (c & 7);
      ushort4 u0, u1;
      u0.x = tile[tc + 0][h ^ xo]; u0.y = tile[tc + 1][h ^ xo];
      u0.z = tile[tc + 2][h ^ xo]; u0.w = tile[tc + 3][h ^ xo];
      u1.x = tile[tc + 4][h ^ xo]; u1.y = tile[tc + 5][h ^ xo];
      u1.z = tile[tc + 6][h ^ xo]; u1.w = tile[tc + 7][h ^ xo];
      int tg = t0 + tc;
      size_t dst = (((size_t)(b * 64 + (tg >> 5)) * 4 + ((tg >> 3) & 3)) * 256 + (h0 + h)) * 8;
      *(ushort4*)(vt + dst) = u0;
      *(ushort4*)(vt + dst + 4) = u1;
    }
  }
}

// ---- Flash attention: R1 structure, occupancy axis only.
// 512-thr blocks, 8 waves x 16 q-rows, q-tile 128, kv-split S=gridDim.z.
// S=4 -> 512 blocks = 2 blocks/CU x 8 waves = 4 waves/SIMD (84 VGPR <= 128).
// K+V double-buffered gl_lds DMA; counted vmcnt(4) acquire; lgkm-only release;
// prefetch distance 2. No setprio (lockstep schedule), no same-BB overlap.
__global__ __launch_bounds__(512, 4)
void attn_kernel(const float* __restrict__ q, const ushort* __restrict__ kt,
                 const ushort* __restrict__ vt, float* __restrict__ out,
                 float* __restrict__ opart, float* __restrict__ lpart) {
  __shared__ ushort Ksh[2][8192];       // [buf][d8][kv32][8]  32 KB
  __shared__ ushort Vsh[2][8192];       // [buf][q4][h256][8]  32 KB
  __shared__ ushort Psh[8][16 * PSTR];  // per-wave P          10 KB

  const int tid = threadIdx.x;
  const int w = tid >> 6, lane = tid & 63, quad = lane >> 4, l16 = lane & 15;
  const int b = blockIdx.x;             // linear%8==b -> XCD affinity
  const int q0 = blockIdx.y * 128;
  const int sp = blockIdx.z;
  const int S = gridDim.z;
  const int niter = (T_ / 32) / S;
  const int kvb = sp * (T_ / S);

  // ---- in-register RoPE of this wave's 16 Q rows into A-frags ----
  bf16x8 aq[8];
  {
    const float* qb = q + ((size_t)(b * T_) + q0 + w * 16) * H_;
    const int t = q0 + w * 16 + l16;
    float qv[8][8];
#pragma unroll
    for (int ks = 0; ks < 8; ++ks) {
      float4 x0 = *(const float4*)(qb + (size_t)l16 * H_ + ks * 32 + quad * 8);
      float4 x1 = *(const float4*)(qb + (size_t)l16 * H_ + ks * 32 + quad * 8 + 4);
      qv[ks][0] = x0.x; qv[ks][1] = x0.y; qv[ks][2] = x0.z; qv[ks][3] = x0.w;
      qv[ks][4] = x1.x; qv[ks][5] = x1.y; qv[ks][6] = x1.z; qv[ks][7] = x1.w;
    }
#pragma unroll
    for (int ks = 0; ks < 4; ++ks)
#pragma unroll
      for (int e = 0; e < 8; ++e) {
        int d = ks * 32 + quad * 8 + e;
        float rv = (float)t * exp2f((float)d * -0.103810252959f) * 0.15915494309f;
        float fr = rv - floorf(rv);
        float sn = __builtin_amdgcn_sinf(fr), cs = __builtin_amdgcn_cosf(fr);
        aq[ks][e]     = (short)f2bf(qv[ks][e] * cs - qv[ks + 4][e] * sn);
        aq[ks + 4][e] = (short)f2bf(qv[ks + 4][e] * cs + qv[ks][e] * sn);
      }
  }

  const f32x4 fzero = {0.f, 0.f, 0.f, 0.f};
  f32x4 O[16], lac = fzero;
#pragma unroll
  for (int ht = 0; ht < 16; ++ht) O[ht] = fzero;
  bf16x8 vones;
#pragma unroll
  for (int i = 0; i < 8; ++i) vones[i] = (short)0x3F80;

  const ushort* ktb = kt + (size_t)(b * 64 + sp * niter) * 8192;
  const ushort* vtb = vt + (size_t)(b * 64 + sp * niter) * 8192;
  const int stoff = tid * 8;            // elems: lane*16B over 512 threads

  // preload tiles 0 and 1 (4 DMA instrs per thread per tile)
#pragma unroll
  for (int tt = 0; tt < 2; ++tt) {
    const ushort* kg = ktb + (size_t)tt * 8192;
    const ushort* vg = vtb + (size_t)tt * 8192;
    gl_lds16(kg + stoff, &Ksh[tt][stoff]);
    gl_lds16(kg + stoff + 4096, &Ksh[tt][stoff + 4096]);
    gl_lds16(vg + stoff, &Vsh[tt][stoff]);
    gl_lds16(vg + stoff + 4096, &Vsh[tt][stoff + 4096]);
  }

  const float arb = SLOPE2 * (float)(q0 + w * 16 + quad * 4);

  for (int it = 0; it < niter; ++it) {
    const int p = it & 1;
    // acquire: tile(it)'s 4 DMAs landed (issued 2 iters ago); tile(it+1)'s 4 in flight
    __builtin_amdgcn_sched_barrier(0);
    if (it == niter - 1) __builtin_amdgcn_s_waitcnt(0x0070);   // vmcnt(0) lgkm(0)
    else                 __builtin_amdgcn_s_waitcnt(0x0F74);   // vmcnt(4)
    __builtin_amdgcn_s_barrier();
    __builtin_amdgcn_sched_barrier(0);

    // QK on Ksh[p]
    f32x4 s[2] = {fzero, fzero};
#pragma unroll
    for (int ks = 0; ks < 8; ++ks)
#pragma unroll
      for (int nt = 0; nt < 2; ++nt) {
        bf16x8 kf = *(const bf16x8*)&Ksh[p][((ks * 4 + quad) * 32 + nt * 16 + l16) * 8];
        s[nt] = MFMA16(aq[ks], kf, s[nt]);
      }

    // p = exp2(s*SCALE2 + SLOPE2*(col-row)) -> wave-private Psh
#pragma unroll
    for (int nt = 0; nt < 2; ++nt) {
      float ac = SLOPE2 * (float)(kvb + it * 32 + nt * 16 + l16);
#pragma unroll
      for (int r = 0; r < 4; ++r) {
        float a0 = ac - arb - SLOPE2 * (float)r;
        float pv = __builtin_amdgcn_exp2f(fmaf(s[nt][r], SCALE2, a0));
        Psh[w][(quad * 4 + r) * PSTR + nt * 16 + l16] = f2bf(pv);
      }
    }

    // PV + rowsum via ones-MFMA (lgkmcnt orders the wave-private write->read)
    bf16x8 pf = *(const bf16x8*)&Psh[w][l16 * PSTR + quad * 8];
    lac = MFMA16(pf, vones, lac);
#pragma unroll
    for (int ht = 0; ht < 16; ++ht) {
      bf16x8 vf = *(const bf16x8*)&Vsh[p][(quad * 256 + ht * 16 + l16) * 8];
      O[ht] = MFMA16(pf, vf, O[ht]);
    }

    // release: drain this wave's LDS reads, then barrier -> buf[p] free
    __builtin_amdgcn_sched_barrier(0);
    __builtin_amdgcn_s_waitcnt(0xC07F);   // lgkmcnt(0) only
    __builtin_amdgcn_s_barrier();
    __builtin_amdgcn_sched_barrier(0);

    // prefetch tile(it+2) into the buffer just freed
    if (it < niter - 2) {
      const ushort* kg = ktb + (size_t)(it + 2) * 8192;
      const ushort* vg = vtb + (size_t)(it + 2) * 8192;
      gl_lds16(kg + stoff, &Ksh[p][stoff]);
      gl_lds16(kg + stoff + 4096, &Ksh[p][stoff + 4096]);
      gl_lds16(vg + stoff, &Vsh[p][stoff]);
      gl_lds16(vg + stoff + 4096, &Vsh[p][stoff + 4096]);
    }
  }

  // epilogue: unnormalized O-partial + l-partial
  float* od = (sp == 0) ? out : (opart + (size_t)(sp - 1) * ELEMS);
  float* ob = od + ((size_t)(b * T_) + q0 + w * 16) * H_;
#pragma unroll
  for (int r = 0; r < 4; ++r) {
    int row = quad * 4 + r;
#pragma unroll
    for (int ht = 0; ht < 16; ++ht)
      ob[(size_t)row * H_ + ht * 16 + l16] = O[ht][r];
  }
  if (l16 == 0) {
#pragma unroll
    for (int r = 0; r < 4; ++r)
      lpart[(size_t)(sp * B_ + b) * T_ + q0 + w * 16 + quad * 4 + r] = lac[r];
  }
}

// ---- combine: out = (O0 + ... + O_{S-1}) / (l0 + ... + l_{S-1}) ----
__global__ void combine_kernel(float* __restrict__ out, const float* __restrict__ opart,
                               const float* __restrict__ lpart, int S) {
  int idx = blockIdx.x * 256 + threadIdx.x;   // over B*T*H/4
  int row = idx >> 6;
  float l = lpart[row];
  for (int s = 1; s < S; ++s) l += lpart[(size_t)s * B_ * T_ + row];
  float inv = 1.0f / l;
  float4 a = ((const float4*)out)[idx];
  for (int s = 1; s < S; ++s) {
    float4 c = ((const float4*)opart)[(size_t)(s - 1) * (ELEMS / 4) + idx];
    a.x += c.x; a.y += c.y; a.z += c.z; a.w += c.w;
  }
  a.x *= inv; a.y *= inv; a.z *= inv; a.w *= inv;
  ((float4*)out)[idx] = a;
}

extern "C" void kernel_launch(void* const* d_in, const int* in_sizes, int n_in,
                              void* d_out, int out_size, void* d_ws, size_t ws_size,
                              hipStream_t stream) {
  const float* q = (const float*)d_in[0];
  const float* k = (const float*)d_in[1];
  const float* v = (const float*)d_in[2];
  float* out = (float*)d_out;

  ushort* kt = (ushort*)d_ws;
  ushort* vt = kt + ELEMS;
  float* opart = (float*)(vt + ELEMS);
  // S=4 needs: kt+vt (2*ELEMS*2B) + 3 opart (3*ELEMS*4B) + lpart (4*B*T*4B)
  const size_t need4 = ELEMS * 4 + 3 * ELEMS * 4 + (size_t)4 * B_ * T_ * 4;
  const int S = (ws_size >= need4) ? 4 : 2;
  float* lpart = opart + (size_t)(S - 1) * ELEMS;

  prep_kernel<<<dim3(2048), 256, 0, stream>>>(k, v, kt, vt);
  attn_kernel<<<dim3(B_, T_ / 128, S), 512, 0, stream>>>(q, kt, vt, out, opart, lpart);
  combine_kernel<<<dim3((B_ * T_ * H_ / 4) / 256), 256, 0, stream>>>(out, opart, lpart, S);
}

// Round 5
// 144.636 us; speedup vs baseline: 1.1748x; 1.0608x over previous
//
#include <hip/hip_runtime.h>

#define B_ 8
#define T_ 2048
#define H_ 256
#define PSTR 40                  // P LDS row stride (elems)
#define SCALE2 0.0901684403f     // (1/16) * log2(e)
#define SLOPE2 0.00563552752f    // 2^-8 * log2(e)
#define ELEMS ((size_t)B_ * T_ * H_)

typedef __attribute__((ext_vector_type(8))) short bf16x8;
typedef __attribute__((ext_vector_type(4))) float f32x4;

#define MFMA16(a, b, c) __builtin_amdgcn_mfma_f32_16x16x32_bf16((a), (b), (c), 0, 0, 0)

__device__ __forceinline__ ushort f2bf(float f) {
  unsigned u = __float_as_uint(f);
  u += 0x7FFFu + ((u >> 16) & 1u);   // RNE; finite inputs
  return (ushort)(u >> 16);
}

// async 16B/lane global->LDS DMA (contiguous: LDS = uniform base + lane*16)
__device__ __forceinline__ void gl_lds16(const ushort* g, ushort* l) {
  __builtin_amdgcn_global_load_lds(
      (const __attribute__((address_space(1))) unsigned int*)g,
      (__attribute__((address_space(3))) unsigned int*)l, 16, 0, 0);
}

// ---- prologue: blocks [0,1024) RoPE(k)->bf16 blocked ktile; [1024,2048) v transpose ----
// ktile layout: [b][it=t/32][d8=d/8][kv=t%32][8]   (16KB contiguous per (b,it) tile)
// vtile layout: [b][it][q4=(t%32)/8][h][8]
__global__ void prep_kernel(const float* __restrict__ k, const float* __restrict__ v,
                            ushort* __restrict__ kt, ushort* __restrict__ vt) {
  __shared__ ushort tile[64][72];
  const int bid = blockIdx.x;
  const int tid = threadIdx.x;
  if (bid < 1024) {
    // K RoPE: thread = (bt, d8); reads 2x32B coalesced, writes 2x16B vector stores
    int idx = bid * 256 + tid;          // over B*T*16
    int d8 = idx & 15;
    int bt = idx >> 4;
    int t = bt & (T_ - 1);
    int b = bt >> 11;
    size_t base = (size_t)bt * H_ + d8 * 8;
    float4 a0 = *(const float4*)(k + base);
    float4 a1 = *(const float4*)(k + base + 4);
    float4 c0 = *(const float4*)(k + base + 128);
    float4 c1 = *(const float4*)(k + base + 132);
    float av[8] = {a0.x, a0.y, a0.z, a0.w, a1.x, a1.y, a1.z, a1.w};
    float cv[8] = {c0.x, c0.y, c0.z, c0.w, c1.x, c1.y, c1.z, c1.w};
    bf16x8 lo, hi;
#pragma unroll
    for (int e = 0; e < 8; ++e) {
      int j = d8 * 8 + e;
      float rv = (float)t * exp2f((float)j * -0.103810252959f) * 0.15915494309f;
      float fr = rv - floorf(rv);
      float sn = __builtin_amdgcn_sinf(fr), cs = __builtin_amdgcn_cosf(fr);
      lo[e] = (short)f2bf(av[e] * cs - cv[e] * sn);
      hi[e] = (short)f2bf(cv[e] * cs + av[e] * sn);
    }
    size_t kdst = (((size_t)(b * 64 + (t >> 5)) * 32 + d8) * 32 + (t & 31)) * 8;
    *(bf16x8*)(kt + kdst) = lo;
    *(bf16x8*)(kt + kdst + 4096) = hi;   // d8 + 16
  } else {
    // V transpose into blocked vtile, 64x64 tiles, XOR-8 swizzle in LDS
    int bid2 = bid - 1024;
    int b = bid2 >> 7, rem = bid2 & 127;
    int h0 = (rem >> 5) * 64, t0 = (rem & 31) * 64;
    int c4 = tid & 15, r0 = tid >> 4;
#pragma unroll
    for (int p = 0; p < 4; ++p) {
      int row = r0 + p * 16;
      const float4 f = *(const float4*)(v + ((size_t)(b * T_ + t0 + row)) * H_ + h0 + c4 * 4);
      ushort4 u;
      u.x = f2bf(f.x); u.y = f2bf(f.y); u.z = f2bf(f.z); u.w = f2bf(f.w);
      *(ushort4*)&tile[row][(c4 * 4) ^ (8 * ((row >> 3) & 7))] = u;
    }
    __syncthreads();
#pragma unroll
    for (int p = 0; p < 2; ++p) {
      int c = tid + p * 256;
      int h = c >> 3, tc = (c & 7) * 8;
      int xo = 8 * (c & 7);
      ushort4 u0, u1;
      u0.x = tile[tc + 0][h ^ xo]; u0.y = tile[tc + 1][h ^ xo];
      u0.z = tile[tc + 2][h ^ xo]; u0.w = tile[tc + 3][h ^ xo];
      u1.x = tile[tc + 4][h ^ xo]; u1.y = tile[tc + 5][h ^ xo];
      u1.z = tile[tc + 6][h ^ xo]; u1.w = tile[tc + 7][h ^ xo];
      int tg = t0 + tc;
      size_t dst = (((size_t)(b * 64 + (tg >> 5)) * 4 + ((tg >> 3) & 3)) * 256 + (h0 + h)) * 8;
      *(ushort4*)(vt + dst) = u0;
      *(ushort4*)(vt + dst + 4) = u1;
    }
  }
}

// ---- Flash attention, kv-split INSIDE the block: 512 thr = 8 waves.
// Waves 0-3 (group 0) do kv[0,1024); waves 4-7 (group 1) do kv[1024,2048);
// both cover the same 64 q-rows (q-tile 64). Grid (8,32)=256 blocks=1/CU,
// 2 waves/SIMD. Per-group private double-buffered K/V (4x16KB). Max-free
// softmax => partials are additive: group 1 dumps O,l to LDS, group 0 sums,
// normalizes, writes out once. NO opart/lpart/combine.
__global__ __launch_bounds__(512, 1)
void attn_kernel(const float* __restrict__ q, const ushort* __restrict__ kt,
                 const ushort* __restrict__ vt, float* __restrict__ out) {
  // 141568 B total LDS, carved manually so the K/V region can be reused
  // as the f32 partial-exchange buffer in the epilogue.
  __shared__ __align__(16) char smem[141568];
  ushort* Kbase = (ushort*)smem;             // [g][buf][8192] ush = 64 KB
  ushort* Vbase = (ushort*)(smem + 65536);   // [g][buf][8192] ush = 64 KB
  ushort* Pbase = (ushort*)(smem + 131072);  // [8][16*PSTR]        10 KB
  float*  Lsh   = (float*)(smem + 141312);   // 64 floats
  float*  Ofl   = (float*)smem;              // epilogue reuse [64][260] f32 (66.6KB)

  const int tid = threadIdx.x;
  const int w = tid >> 6, lane = tid & 63, quad = lane >> 4, l16 = lane & 15;
  const int g = w >> 2;                 // kv-half group
  const int wl = w & 3;                 // wave index within group
  const int gt = tid & 255;             // thread index within group
  const int b = blockIdx.x;             // linear%8==b -> XCD affinity
  const int q0 = blockIdx.y * 64;
  const int kvb0 = g * (T_ / 2);

  ushort* Ksh = Kbase + g * 16384;      // this group's [buf][8192]
  ushort* Vsh = Vbase + g * 16384;
  ushort* Psh = Pbase + w * (16 * PSTR);

  // ---- in-register RoPE of this wave's 16 Q rows into A-frags ----
  bf16x8 aq[8];
  {
    const float* qb = q + ((size_t)(b * T_) + q0 + wl * 16) * H_;
    const int t = q0 + wl * 16 + l16;
    float qv[8][8];
#pragma unroll
    for (int ks = 0; ks < 8; ++ks) {
      float4 x0 = *(const float4*)(qb + (size_t)l16 * H_ + ks * 32 + quad * 8);
      float4 x1 = *(const float4*)(qb + (size_t)l16 * H_ + ks * 32 + quad * 8 + 4);
      qv[ks][0] = x0.x; qv[ks][1] = x0.y; qv[ks][2] = x0.z; qv[ks][3] = x0.w;
      qv[ks][4] = x1.x; qv[ks][5] = x1.y; qv[ks][6] = x1.z; qv[ks][7] = x1.w;
    }
#pragma unroll
    for (int ks = 0; ks < 4; ++ks)
#pragma unroll
      for (int e = 0; e < 8; ++e) {
        int d = ks * 32 + quad * 8 + e;
        float rv = (float)t * exp2f((float)d * -0.103810252959f) * 0.15915494309f;
        float fr = rv - floorf(rv);
        float sn = __builtin_amdgcn_sinf(fr), cs = __builtin_amdgcn_cosf(fr);
        aq[ks][e]     = (short)f2bf(qv[ks][e] * cs - qv[ks + 4][e] * sn);
        aq[ks + 4][e] = (short)f2bf(qv[ks + 4][e] * cs + qv[ks][e] * sn);
      }
  }

  const f32x4 fzero = {0.f, 0.f, 0.f, 0.f};
  f32x4 O[16], lac = fzero;
#pragma unroll
  for (int ht = 0; ht < 16; ++ht) O[ht] = fzero;
  bf16x8 vones;
#pragma unroll
  for (int i = 0; i < 8; ++i) vones[i] = (short)0x3F80;

  // group g streams tiles [g*32, g*32+32) of this b
  const ushort* ktb = kt + (size_t)(b * 64 + g * 32) * 8192;
  const ushort* vtb = vt + (size_t)(b * 64 + g * 32) * 8192;
  const int stoff = gt * 8;             // elems: 16B/lane over 256 group threads

  // preload tiles 0 and 1 (8 DMA instrs per thread per tile: 4 K + 4 V)
#pragma unroll
  for (int tt = 0; tt < 2; ++tt) {
    const ushort* kg = ktb + (size_t)tt * 8192;
    const ushort* vg = vtb + (size_t)tt * 8192;
#pragma unroll
    for (int i = 0; i < 4; ++i) {
      gl_lds16(kg + stoff + i * 2048, Ksh + tt * 8192 + stoff + i * 2048);
      gl_lds16(vg + stoff + i * 2048, Vsh + tt * 8192 + stoff + i * 2048);
    }
  }

  const float arb = SLOPE2 * (float)(q0 + wl * 16 + quad * 4);

  for (int it = 0; it < 32; ++it) {
    const int p = it & 1;
    // acquire: tile(it)'s 8 DMAs landed (issued 2 iters ago); tile(it+1)'s 8 in flight
    __builtin_amdgcn_sched_barrier(0);
    if (it == 31) __builtin_amdgcn_s_waitcnt(0x0070);   // vmcnt(0) lgkm(0)
    else          __builtin_amdgcn_s_waitcnt(0x0F78);   // vmcnt(8)
    __builtin_amdgcn_s_barrier();
    __builtin_amdgcn_sched_barrier(0);

    // QK on Ksh[p]
    f32x4 s[2] = {fzero, fzero};
#pragma unroll
    for (int ks = 0; ks < 8; ++ks)
#pragma unroll
      for (int nt = 0; nt < 2; ++nt) {
        bf16x8 kf = *(const bf16x8*)&Ksh[p * 8192 + ((ks * 4 + quad) * 32 + nt * 16 + l16) * 8];
        s[nt] = MFMA16(aq[ks], kf, s[nt]);
      }

    // p = exp2(s*SCALE2 + SLOPE2*(col-row)) -> wave-private Psh
#pragma unroll
    for (int nt = 0; nt < 2; ++nt) {
      float ac = SLOPE2 * (float)(kvb0 + it * 32 + nt * 16 + l16);
#pragma unroll
      for (int r = 0; r < 4; ++r) {
        float a0 = ac - arb - SLOPE2 * (float)r;
        float pv = __builtin_amdgcn_exp2f(fmaf(s[nt][r], SCALE2, a0));
        Psh[(quad * 4 + r) * PSTR + nt * 16 + l16] = f2bf(pv);
      }
    }

    // PV + rowsum via ones-MFMA (lgkmcnt orders the wave-private write->read)
    bf16x8 pf = *(const bf16x8*)&Psh[l16 * PSTR + quad * 8];
    lac = MFMA16(pf, vones, lac);
#pragma unroll
    for (int ht = 0; ht < 16; ++ht) {
      bf16x8 vf = *(const bf16x8*)&Vsh[p * 8192 + (quad * 256 + ht * 16 + l16) * 8];
      O[ht] = MFMA16(pf, vf, O[ht]);
    }

    // release: drain this wave's LDS reads, then barrier -> buf[p] free
    __builtin_amdgcn_sched_barrier(0);
    __builtin_amdgcn_s_waitcnt(0xC07F);   // lgkmcnt(0) only
    __builtin_amdgcn_s_barrier();
    __builtin_amdgcn_sched_barrier(0);

    // prefetch tile(it+2) into the buffer just freed
    if (it < 30) {
      const ushort* kg = ktb + (size_t)(it + 2) * 8192;
      const ushort* vg = vtb + (size_t)(it + 2) * 8192;
#pragma unroll
      for (int i = 0; i < 4; ++i) {
        gl_lds16(kg + stoff + i * 2048, Ksh + p * 8192 + stoff + i * 2048);
        gl_lds16(vg + stoff + i * 2048, Vsh + p * 8192 + stoff + i * 2048);
      }
    }
  }

  // ---- in-LDS combine: additive partials (max-free softmax) ----
  // After the final release barrier all K/V reads are retired; group 1 may
  // overwrite the K/V region with its f32 partials (stride 260 f32: the
  // quad stride 4*260 % 32 banks = 16 -> worst 2-way conflict, free).
  if (g == 1) {
#pragma unroll
    for (int r = 0; r < 4; ++r) {
      int row = wl * 16 + quad * 4 + r;
#pragma unroll
      for (int ht = 0; ht < 16; ++ht)
        Ofl[row * 260 + ht * 16 + l16] = O[ht][r];
      if (l16 == 0) Lsh[row] = lac[r];
    }
  }
  __syncthreads();
  if (g == 0) {
    float* ob = out + ((size_t)(b * T_) + q0 + wl * 16) * H_;
#pragma unroll
    for (int r = 0; r < 4; ++r) {
      int row = wl * 16 + quad * 4 + r;
      float inv = 1.0f / (lac[r] + Lsh[row]);
#pragma unroll
      for (int ht = 0; ht < 16; ++ht)
        ob[(size_t)(quad * 4 + r) * H_ + ht * 16 + l16] =
            (O[ht][r] + Ofl[row * 260 + ht * 16 + l16]) * inv;
    }
  }
}

extern "C" void kernel_launch(void* const* d_in, const int* in_sizes, int n_in,
                              void* d_out, int out_size, void* d_ws, size_t ws_size,
                              hipStream_t stream) {
  const float* q = (const float*)d_in[0];
  const float* k = (const float*)d_in[1];
  const float* v = (const float*)d_in[2];
  float* out = (float*)d_out;

  ushort* kt = (ushort*)d_ws;
  ushort* vt = kt + ELEMS;

  prep_kernel<<<dim3(2048), 256, 0, stream>>>(k, v, kt, vt);
  attn_kernel<<<dim3(B_, T_ / 64), 512, 0, stream>>>(q, kt, vt, out);
}